// Round 1
// baseline (4657.698 us; speedup 1.0000x reference)
//
#include <hip/hip_runtime.h>
#include <hip/hip_bf16.h>

// Problem constants (also re-derived from in_sizes in kernel_launch)
#define TT 12
#define HDIM 128
#define ODIM 12
#define MT 32          // LSTM nodes per block
#define TPAD 36        // padded row stride (floats) for transposed LDS h tiles (row bytes = 144, 16B-aligned)

__device__ __forceinline__ float sigf(float x) { return 1.f / (1.f + expf(-x)); }

// acc[mi][g] += hT[k][m0+mi] * WT[k][g*128+jj]  over k=0..127
__device__ __forceinline__ void gemm_step(const float* __restrict__ hT,
                                          const float* __restrict__ WT,
                                          int jj, int m0, float acc[16][4])
{
    for (int k = 0; k < 128; ++k) {
        const float* hr = hT + k * TPAD + m0;
        float a[16];
#pragma unroll
        for (int q = 0; q < 4; ++q) {
            float4 v = *(const float4*)(hr + 4 * q);
            a[4 * q + 0] = v.x; a[4 * q + 1] = v.y; a[4 * q + 2] = v.z; a[4 * q + 3] = v.w;
        }
        float bw[4];
#pragma unroll
        for (int g = 0; g < 4; ++g) bw[g] = WT[k * 512 + (g << 7) + jj];
#pragma unroll
        for (int mi = 0; mi < 16; ++mi)
#pragma unroll
            for (int g = 0; g < 4; ++g) acc[mi][g] = fmaf(a[mi], bw[g], acc[mi][g]);
    }
}

// Fused 2-layer LSTM over all 12 timesteps. One block = 32 nodes.
// h-state kept transposed in LDS (hT[k][m]); c-state in registers.
__global__ __launch_bounds__(256) void lstm_kernel(
    const float* __restrict__ x,      // [N][12][2]
    const float* __restrict__ Wih0,   // [512][2]
    const float* __restrict__ WT0,    // [128][512] = Whh0^T
    const float* __restrict__ WT1,    // [128][512] = Wih1^T
    const float* __restrict__ WT2,    // [128][512] = Whh1^T
    const float* __restrict__ bc0,    // [512] bih0+bhh0
    const float* __restrict__ bc1,    // [512] bih1+bhh1
    float* __restrict__ hbuf,         // [N][128] out: h1 at t=T-1
    int N)
{
    __shared__ float hT0[128 * TPAD];
    __shared__ float hT1[128 * TPAD];
    __shared__ float xs[MT * 2];

    const int tid = threadIdx.x;
    const int jj  = tid & 127;        // output channel j
    const int mh  = tid >> 7;         // 0/1 -> node half
    const int m0  = mh << 4;
    const int nbase = blockIdx.x * MT;

    for (int i = tid; i < 128 * TPAD; i += 256) { hT0[i] = 0.f; hT1[i] = 0.f; }

    float wx0[4], wx1[4], br0[4], br1[4];
#pragma unroll
    for (int g = 0; g < 4; ++g) {
        int row = (g << 7) + jj;
        wx0[g] = Wih0[row * 2 + 0];
        wx1[g] = Wih0[row * 2 + 1];
        br0[g] = bc0[row];
        br1[g] = bc1[row];
    }

    float c0[16], c1[16];
#pragma unroll
    for (int i = 0; i < 16; ++i) { c0[i] = 0.f; c1[i] = 0.f; }

    __syncthreads();

    for (int t = 0; t < TT; ++t) {
        if (tid < MT * 2) {
            int m = tid >> 1, comp = tid & 1;
            int n = nbase + m;
            xs[tid] = (n < N) ? x[(n * TT + t) * 2 + comp] : 0.f;
        }
        __syncthreads();                       // B0: xs ready; prev hT1 write visible

        // ---------- layer 0 ----------
        float acc[16][4];
#pragma unroll
        for (int mi = 0; mi < 16; ++mi) {
            float xa = xs[(m0 + mi) * 2 + 0], xb = xs[(m0 + mi) * 2 + 1];
#pragma unroll
            for (int g = 0; g < 4; ++g) acc[mi][g] = br0[g] + wx0[g] * xa + wx1[g] * xb;
        }
        gemm_step(hT0, WT0, jj, m0, acc);
        __syncthreads();                       // B1: hT0 reads done

        float hn[16];
#pragma unroll
        for (int mi = 0; mi < 16; ++mi) {
            float ig = sigf(acc[mi][0]);
            float fg = sigf(acc[mi][1]);
            float gg = tanhf(acc[mi][2]);
            float og = sigf(acc[mi][3]);
            float cn = fg * c0[mi] + ig * gg;
            c0[mi] = cn;
            hn[mi] = og * tanhf(cn);
        }
        {
            float* hw = &hT0[jj * TPAD + m0];
#pragma unroll
            for (int mi = 0; mi < 16; ++mi) hw[mi] = hn[mi];
        }
        __syncthreads();                       // B2: new hT0 visible

        // ---------- layer 1 ----------
#pragma unroll
        for (int mi = 0; mi < 16; ++mi)
#pragma unroll
            for (int g = 0; g < 4; ++g) acc[mi][g] = br1[g];
        gemm_step(hT0, WT1, jj, m0, acc);      // input term: h0_t @ Wih1^T
        gemm_step(hT1, WT2, jj, m0, acc);      // recurrent:  h1_{t-1} @ Whh1^T
        __syncthreads();                       // B3: hT1 reads done

#pragma unroll
        for (int mi = 0; mi < 16; ++mi) {
            float ig = sigf(acc[mi][0]);
            float fg = sigf(acc[mi][1]);
            float gg = tanhf(acc[mi][2]);
            float og = sigf(acc[mi][3]);
            float cn = fg * c1[mi] + ig * gg;
            c1[mi] = cn;
            hn[mi] = og * tanhf(cn);
        }
        {
            float* hw = &hT1[jj * TPAD + m0];
#pragma unroll
            for (int mi = 0; mi < 16; ++mi) hw[mi] = hn[mi];
        }
        // next-iteration B0 orders this write before any hT1 read
    }
    __syncthreads();

#pragma unroll
    for (int mi = 0; mi < 16; ++mi) {
        int n = nbase + m0 + mi;
        if (n < N) hbuf[n * HDIM + jj] = hT1[jj * TPAD + m0 + mi];
    }
}

// Weight transposes + combined biases
__global__ void prep_kernel(const float* __restrict__ Whh0, const float* __restrict__ Wih1,
                            const float* __restrict__ Whh1,
                            const float* __restrict__ bih0, const float* __restrict__ bhh0,
                            const float* __restrict__ bih1, const float* __restrict__ bhh1,
                            float* __restrict__ WT0, float* __restrict__ WT1, float* __restrict__ WT2,
                            float* __restrict__ bc0, float* __restrict__ bc1)
{
    int idx = blockIdx.x * 256 + threadIdx.x;
    if (idx < 512 * 128) {
        int j = idx >> 7, k = idx & 127;
        WT0[k * 512 + j] = Whh0[idx];
        WT1[k * 512 + j] = Wih1[idx];
        WT2[k * 512 + j] = Whh1[idx];
    }
    if (idx < 512) {
        bc0[idx] = bih0[idx] + bhh0[idx];
        bc1[idx] = bih1[idx] + bhh1[idx];
    }
}

__global__ void deg_count_kernel(const int* __restrict__ ei, int* __restrict__ degi, int E)
{
    int e = blockIdx.x * 256 + threadIdx.x;
    if (e < E) atomicAdd(&degi[ei[E + e]], 1);
}

// Allocate contiguous CSR rows per node without a global scan:
// wave-level inclusive scan + one atomicAdd per wave. Also computes dinv.
__global__ void row_alloc_kernel(const int* __restrict__ degi, int* __restrict__ row_ptr,
                                 float* __restrict__ dinv, int* __restrict__ counter, int N)
{
    int n = blockIdx.x * 256 + threadIdx.x;
    int lane = threadIdx.x & 63;
    int v = (n < N) ? degi[n] : 0;
    int incl = v;
    for (int off = 1; off < 64; off <<= 1) {
        int u = __shfl_up(incl, off);
        if (lane >= off) incl += u;
    }
    int base = 0;
    if (lane == 63) base = atomicAdd(counter, incl);
    base = __shfl(base, 63);
    if (n < N) {
        row_ptr[n] = base + (incl - v);
        dinv[n] = rsqrtf((float)(v + 1));   // +1 self-loop
    }
}

__global__ void csr_fill_kernel(const int* __restrict__ ei, const int* __restrict__ row_ptr,
                                int* __restrict__ fill, int* __restrict__ csr_src, int E)
{
    int e = blockIdx.x * 256 + threadIdx.x;
    if (e < E) {
        int d = ei[E + e];
        int p = atomicAdd(&fill[d], 1);
        csr_src[row_ptr[d] + p] = ei[e];
    }
}

// Y[N][128] = X[N][128] @ W[128][128]; block = 32 rows, thread -> (2 cols x 8 rows)
__global__ __launch_bounds__(256) void gemm128_kernel(const float* __restrict__ X,
                                                      const float* __restrict__ W,
                                                      float* __restrict__ Y, int N)
{
    __shared__ float XT[128 * TPAD];
    const int tid = threadIdx.x;
    const int nbase = blockIdx.x * 32;
    for (int idx = tid; idx < 32 * 128; idx += 256) {
        int m = idx >> 7, k = idx & 127;
        int n = nbase + m;
        XT[k * TPAD + m] = (n < N) ? X[n * HDIM + k] : 0.f;
    }
    __syncthreads();
    const int c  = tid & 63;
    const int mb = (tid >> 6) << 3;   // 0,8,16,24
    float acc[8][2];
#pragma unroll
    for (int i = 0; i < 8; ++i) { acc[i][0] = 0.f; acc[i][1] = 0.f; }
    for (int k = 0; k < 128; ++k) {
        const float* xr = &XT[k * TPAD + mb];
        float4 a0 = *(const float4*)(xr);
        float4 a1 = *(const float4*)(xr + 4);
        float a[8] = {a0.x, a0.y, a0.z, a0.w, a1.x, a1.y, a1.z, a1.w};
        float b0 = W[k * HDIM + c];
        float b1 = W[k * HDIM + c + 64];
#pragma unroll
        for (int i = 0; i < 8; ++i) {
            acc[i][0] = fmaf(a[i], b0, acc[i][0]);
            acc[i][1] = fmaf(a[i], b1, acc[i][1]);
        }
    }
#pragma unroll
    for (int i = 0; i < 8; ++i) {
        int n = nbase + mb + i;
        if (n < N) {
            Y[n * HDIM + c]      = acc[i][0];
            Y[n * HDIM + c + 64] = acc[i][1];
        }
    }
}

// Y[N][12] = X[N][128] @ W2[128][12]; thread per (n,c)
__global__ void gemm12_kernel(const float* __restrict__ X, const float* __restrict__ W2,
                              float* __restrict__ Y, int N)
{
    int idx = blockIdx.x * 256 + threadIdx.x;
    int n = idx / ODIM, c = idx - n * ODIM;
    if (n >= N) return;
    float acc = 0.f;
    for (int k = 0; k < 128; ++k) acc = fmaf(X[n * HDIM + k], W2[k * ODIM + c], acc);
    Y[n * ODIM + c] = acc;
}

// out[n][c] = relu?( sum_{e in in(n)} hW[src_e][c]*dinv[src]*dinv[n] + hW[n][c]*dinv[n]^2 + bias[c] )
__global__ __launch_bounds__(128) void agg128_kernel(const float* __restrict__ hW,
        const int* __restrict__ row_ptr, const int* __restrict__ degi,
        const int* __restrict__ csr_src, const float* __restrict__ dinv,
        const float* __restrict__ bias, float* __restrict__ out, int N, int do_relu)
{
    int n = blockIdx.x;
    int c = threadIdx.x;
    float dn = dinv[n];
    float acc = hW[n * HDIM + c] * dn * dn;
    int start = row_ptr[n];
    int cnt = degi[n];
    for (int i = 0; i < cnt; ++i) {
        int s = csr_src[start + i];
        acc = fmaf(hW[s * HDIM + c], dinv[s] * dn, acc);
    }
    float v = acc + bias[c];
    if (do_relu) v = fmaxf(v, 0.f);
    out[n * HDIM + c] = v;
}

__global__ void agg12_kernel(const float* __restrict__ hW, const int* __restrict__ row_ptr,
        const int* __restrict__ degi, const int* __restrict__ csr_src,
        const float* __restrict__ dinv, const float* __restrict__ b2,
        float* __restrict__ out, int N)
{
    int idx = blockIdx.x * 256 + threadIdx.x;
    int n = idx / ODIM, c = idx - n * ODIM;
    if (n >= N) return;
    float dn = dinv[n];
    float acc = hW[n * ODIM + c] * dn * dn;
    int start = row_ptr[n], cnt = degi[n];
    for (int i = 0; i < cnt; ++i) {
        int s = csr_src[start + i];
        acc = fmaf(hW[s * ODIM + c], dinv[s] * dn, acc);
    }
    out[n * ODIM + c] = acc + b2[c];
}

extern "C" void kernel_launch(void* const* d_in, const int* in_sizes, int n_in,
                              void* d_out, int out_size, void* d_ws, size_t ws_size,
                              hipStream_t stream)
{
    const float* x     = (const float*)d_in[0];
    const int*   ei    = (const int*)d_in[1];
    const float* Wih0  = (const float*)d_in[2];
    const float* Whh0  = (const float*)d_in[3];
    const float* bih0  = (const float*)d_in[4];
    const float* bhh0  = (const float*)d_in[5];
    const float* Wih1  = (const float*)d_in[6];
    const float* Whh1  = (const float*)d_in[7];
    const float* bih1  = (const float*)d_in[8];
    const float* bhh1  = (const float*)d_in[9];
    const float* W0    = (const float*)d_in[10];
    const float* b0    = (const float*)d_in[11];
    const float* W1    = (const float*)d_in[12];
    const float* b1    = (const float*)d_in[13];
    const float* W2    = (const float*)d_in[14];
    const float* b2    = (const float*)d_in[15];
    float* out = (float*)d_out;

    const int N = in_sizes[0] / (TT * 2);     // 50000
    const int E = in_sizes[1] / 2;            // 800000

    // ---- workspace layout (floats then ints) ----
    float* ws   = (float*)d_ws;
    float* WT0  = ws;                          // 128*512
    float* WT1  = WT0 + 65536;
    float* WT2  = WT1 + 65536;
    float* bc0  = WT2 + 65536;                 // 512
    float* bc1  = bc0 + 512;
    float* hbuf = bc1 + 512;                   // N*128
    float* buf1 = hbuf + (size_t)N * HDIM;     // N*128
    float* buf2 = buf1 + (size_t)N * HDIM;     // N*128
    float* dinv = buf2 + (size_t)N * HDIM;     // N
    int* degi    = (int*)(dinv + N);           // N
    int* fill    = degi + N;                   // N
    int* counter = fill + N;                   // 1
    int* row_ptr = counter + 1;                // N
    int* csr_src = row_ptr + N;                // E

    // zero degi, fill, counter (contiguous)
    hipMemsetAsync(degi, 0, (size_t)(2 * N + 1) * sizeof(int), stream);

    prep_kernel<<<(512 * 128 + 255) / 256, 256, 0, stream>>>(
        Whh0, Wih1, Whh1, bih0, bhh0, bih1, bhh1, WT0, WT1, WT2, bc0, bc1);

    lstm_kernel<<<(N + MT - 1) / MT, 256, 0, stream>>>(
        x, Wih0, WT0, WT1, WT2, bc0, bc1, hbuf, N);

    deg_count_kernel<<<(E + 255) / 256, 256, 0, stream>>>(ei, degi, E);
    row_alloc_kernel<<<(N + 255) / 256, 256, 0, stream>>>(degi, row_ptr, dinv, counter, N);
    csr_fill_kernel<<<(E + 255) / 256, 256, 0, stream>>>(ei, row_ptr, fill, csr_src, E);

    // GCN layer 0
    gemm128_kernel<<<(N + 31) / 32, 256, 0, stream>>>(hbuf, W0, buf1, N);
    agg128_kernel<<<N, 128, 0, stream>>>(buf1, row_ptr, degi, csr_src, dinv, b0, buf2, N, 1);
    // GCN layer 1
    gemm128_kernel<<<(N + 31) / 32, 256, 0, stream>>>(buf2, W1, buf1, N);
    agg128_kernel<<<N, 128, 0, stream>>>(buf1, row_ptr, degi, csr_src, dinv, b1, buf2, N, 1);
    // GCN layer 2 (transform first: 12-wide messages)
    gemm12_kernel<<<((size_t)N * ODIM + 255) / 256, 256, 0, stream>>>(buf2, W2, buf1, N);
    agg12_kernel<<<((size_t)N * ODIM + 255) / 256, 256, 0, stream>>>(
        buf1, row_ptr, degi, csr_src, dinv, b2, out, N);
}

// Round 2
// 2211.400 us; speedup vs baseline: 2.1062x; 2.1062x over previous
//
#include <hip/hip_runtime.h>
#include <hip/hip_bf16.h>

#define TT 12
#define HDIM 128
#define ODIM 12
#define MB 64          // LSTM nodes per block
#define STR 148        // hA row stride in bf16 elements (296 B: 8B-aligned, 2-way-bank-free b64 reads)
#define TPAD 36        // fp32 GCN gemm LDS pad

typedef short bf16x8 __attribute__((ext_vector_type(8)));
typedef short bf16x4 __attribute__((ext_vector_type(4)));
typedef float f32x16 __attribute__((ext_vector_type(16)));

__device__ __forceinline__ float fastrcp(float x) { return __builtin_amdgcn_rcpf(x); }
__device__ __forceinline__ float sigf(float x) { return fastrcp(1.f + __expf(-x)); }
__device__ __forceinline__ float tanh_fast(float x) { return 1.f - 2.f * fastrcp(1.f + __expf(2.f * x)); }
__device__ __forceinline__ unsigned short f2bf(float f) {
    union { float f; unsigned int u; } v; v.f = f;
    unsigned int r = v.u + 0x7FFFu + ((v.u >> 16) & 1u);
    return (unsigned short)(r >> 16);
}

// ---------------- weight pre-pack into MFMA B-fragment order ----------------
// Wpk slot layout: slot = {mat0: cb*9+s (0..143)} {mat1: +144} {mat2: cb*8+s +288}
// element = Wpk[(slot*64 + lane)*8 + j];  B[k][col]: col=cb*32+(lane&31), k=s*16+(lane>>5)*8+j
// mat0 (z0, K=144): k<128 -> Whh0[col][k]; k=128/129 -> Wih0[col][0/1]; k=130 -> bih0+bhh0; else 0
// mat1 (z1 input, K=144): k<128 -> Wih1[col][k]; k=130 -> bih1+bhh1; else 0
// mat2 (z1 recur, K=128): Whh1[col][k]
__global__ void pack_kernel(const float* __restrict__ Wih0, const float* __restrict__ Whh0,
                            const float* __restrict__ bih0, const float* __restrict__ bhh0,
                            const float* __restrict__ Wih1, const float* __restrict__ Whh1,
                            const float* __restrict__ bih1, const float* __restrict__ bhh1,
                            unsigned short* __restrict__ Wpk)
{
    int idx = blockIdx.x * 256 + threadIdx.x;
    if (idx >= 416 * 64) return;
    int lane = idx & 63;
    int slot = idx >> 6;
    int mat, cb, s;
    if (slot < 144)      { mat = 0; cb = slot / 9; s = slot % 9; }
    else if (slot < 288) { mat = 1; cb = (slot - 144) / 9; s = (slot - 144) % 9; }
    else                 { mat = 2; cb = (slot - 288) / 8; s = (slot - 288) % 8; }
    int col = cb * 32 + (lane & 31);
#pragma unroll
    for (int j = 0; j < 8; ++j) {
        int k = s * 16 + ((lane >> 5) << 3) + j;
        float v = 0.f;
        if (mat == 0) {
            if (k < 128)      v = Whh0[col * 128 + k];
            else if (k == 128) v = Wih0[col * 2 + 0];
            else if (k == 129) v = Wih0[col * 2 + 1];
            else if (k == 130) v = bih0[col] + bhh0[col];
        } else if (mat == 1) {
            if (k < 128)      v = Wih1[col * 128 + k];
            else if (k == 130) v = bih1[col] + bhh1[col];
        } else {
            v = Whh1[col * 128 + k];
        }
        Wpk[((size_t)(slot * 64 + lane) << 3) + j] = f2bf(v);
    }
}

// ---------------- fused 2-layer LSTM, bf16 MFMA ----------------
template<int S>
__device__ __forceinline__ void mfma_gemm(const unsigned short* __restrict__ hA,
                                          const unsigned short* __restrict__ Bbase,
                                          int w, int ln, f32x16 (&acc)[2][4])
{
    const int ln31 = ln & 31, half = ln >> 5;
#pragma unroll
    for (int s = 0; s < S; ++s) {
        bf16x8 a[2];
#pragma unroll
        for (int rb = 0; rb < 2; ++rb) {
            const unsigned short* pa = hA + (rb * 32 + ln31) * STR + s * 16 + half * 8;
            bf16x4 lo = *(const bf16x4*)pa;
            bf16x4 hi = *(const bf16x4*)(pa + 4);
            a[rb] = __builtin_shufflevector(lo, hi, 0, 1, 2, 3, 4, 5, 6, 7);
        }
#pragma unroll
        for (int g = 0; g < 4; ++g) {
            int cb = g * 4 + w;
            bf16x8 b = *(const bf16x8*)(Bbase + (((cb * S + s) * 64 + ln) << 3));
            acc[0][g] = __builtin_amdgcn_mfma_f32_32x32x16_bf16(a[0], b, acc[0][g], 0, 0, 0);
            acc[1][g] = __builtin_amdgcn_mfma_f32_32x32x16_bf16(a[1], b, acc[1][g], 0, 0, 0);
        }
    }
}

__device__ __forceinline__ void zero_acc(f32x16 (&acc)[2][4])
{
#pragma unroll
    for (int rb = 0; rb < 2; ++rb)
#pragma unroll
        for (int g = 0; g < 4; ++g)
#pragma unroll
            for (int e = 0; e < 16; ++e) acc[rb][g][e] = 0.f;
}

__global__ __launch_bounds__(256, 2) void lstm_mfma_kernel(
    const float* __restrict__ x,              // [N][12][2]
    const unsigned short* __restrict__ Wpk,   // packed B fragments
    float* __restrict__ hbuf,                 // [N][128] out (fp32 h1 at t=11)
    int N)
{
    __shared__ unsigned short hA0[2][MB * STR];
    __shared__ unsigned short hA1[MB * STR];
    __shared__ unsigned short xls[MB * TT * 2];   // bf16 x, layout [m][t][c] (same linear order as global)

    const int tid = threadIdx.x;
    const int w = tid >> 6;
    const int ln = tid & 63;
    const int ln31 = ln & 31;
    const int half = ln >> 5;
    const int col = w * 32 + ln31;
    const int nbase = blockIdx.x * MB;

    // stage x for this block (coalesced), bf16
    for (int i = tid; i < MB * TT * 2; i += 256) {
        int n = nbase + i / (TT * 2);
        float v = (n < N) ? x[(size_t)nbase * (TT * 2) + i] : 0.f;
        xls[i] = f2bf(v);
    }
    for (int i = tid; i < MB * STR; i += 256) { hA0[0][i] = 0; hA0[1][i] = 0; hA1[i] = 0; }
    __syncthreads();
    // constant 1.0 column (k=130) for the bias row; x_0 at k=128..129
    if (tid < MB) { hA0[0][tid * STR + 130] = 0x3F80; hA0[1][tid * STR + 130] = 0x3F80; }
    if (tid < MB * 2) { int m = tid >> 1, c = tid & 1; hA0[0][m * STR + 128 + c] = xls[m * (TT * 2) + c]; }

    float c0[2][16], c1[2][16];
#pragma unroll
    for (int rb = 0; rb < 2; ++rb)
#pragma unroll
        for (int r = 0; r < 16; ++r) { c0[rb][r] = 0.f; c1[rb][r] = 0.f; }

    __syncthreads();

    int p = 0;
    for (int t = 0; t < TT; ++t) {
        int q = p ^ 1;
        // ---- layer 0: z0 = [h0_{t-1}, x_t, 1] @ B0 ----
        f32x16 acc[2][4];
        zero_acc(acc);
        mfma_gemm<9>(hA0[p], Wpk, w, ln, acc);
        // epilogue 0 -> h0_t into hA0[q]
#pragma unroll
        for (int rb = 0; rb < 2; ++rb)
#pragma unroll
            for (int r = 0; r < 16; ++r) {
                float cn = sigf(acc[rb][1][r]) * c0[rb][r] + sigf(acc[rb][0][r]) * tanh_fast(acc[rb][2][r]);
                c0[rb][r] = cn;
                float h = sigf(acc[rb][3][r]) * tanh_fast(cn);
                int row = (r & 3) + 8 * (r >> 2) + 4 * half + rb * 32;
                hA0[q][row * STR + col] = f2bf(h);
            }
        if (t + 1 < TT) {   // stage x_{t+1} alongside h0_t
            if (tid < MB * 2) { int m = tid >> 1, c = tid & 1; hA0[q][m * STR + 128 + c] = xls[m * (TT * 2) + (t + 1) * 2 + c]; }
        }
        __syncthreads();   // h0_t + x_{t+1} visible; all waves done reading hA0[p]

        // ---- layer 1: z1 = [h0_t, ., 1] @ B1a + h1_{t-1} @ B1b ----
        zero_acc(acc);
        mfma_gemm<9>(hA0[q], Wpk + 73728, w, ln, acc);
        mfma_gemm<8>(hA1,    Wpk + 147456, w, ln, acc);
        __syncthreads();   // all waves done reading hA1

#pragma unroll
        for (int rb = 0; rb < 2; ++rb)
#pragma unroll
            for (int r = 0; r < 16; ++r) {
                float cn = sigf(acc[rb][1][r]) * c1[rb][r] + sigf(acc[rb][0][r]) * tanh_fast(acc[rb][2][r]);
                c1[rb][r] = cn;
                float h = sigf(acc[rb][3][r]) * tanh_fast(cn);
                int row = (r & 3) + 8 * (r >> 2) + 4 * half + rb * 32;
                if (t + 1 < TT) {
                    hA1[row * STR + col] = f2bf(h);
                } else {
                    int n = nbase + row;
                    if (n < N) hbuf[n * HDIM + col] = h;   // fp32 h for the GCN
                }
            }
        p = q;
    }
}

// ---------------- GCN (unchanged from R1: passed, minor cost) ----------------
__global__ void deg_count_kernel(const int* __restrict__ ei, int* __restrict__ degi, int E)
{
    int e = blockIdx.x * 256 + threadIdx.x;
    if (e < E) atomicAdd(&degi[ei[E + e]], 1);
}

__global__ void row_alloc_kernel(const int* __restrict__ degi, int* __restrict__ row_ptr,
                                 float* __restrict__ dinv, int* __restrict__ counter, int N)
{
    int n = blockIdx.x * 256 + threadIdx.x;
    int lane = threadIdx.x & 63;
    int v = (n < N) ? degi[n] : 0;
    int incl = v;
    for (int off = 1; off < 64; off <<= 1) {
        int u = __shfl_up(incl, off);
        if (lane >= off) incl += u;
    }
    int base = 0;
    if (lane == 63) base = atomicAdd(counter, incl);
    base = __shfl(base, 63);
    if (n < N) {
        row_ptr[n] = base + (incl - v);
        dinv[n] = rsqrtf((float)(v + 1));
    }
}

__global__ void csr_fill_kernel(const int* __restrict__ ei, const int* __restrict__ row_ptr,
                                int* __restrict__ fill, int* __restrict__ csr_src, int E)
{
    int e = blockIdx.x * 256 + threadIdx.x;
    if (e < E) {
        int d = ei[E + e];
        int p = atomicAdd(&fill[d], 1);
        csr_src[row_ptr[d] + p] = ei[e];
    }
}

__global__ __launch_bounds__(256) void gemm128_kernel(const float* __restrict__ X,
                                                      const float* __restrict__ W,
                                                      float* __restrict__ Y, int N)
{
    __shared__ float XT[128 * TPAD];
    const int tid = threadIdx.x;
    const int nbase = blockIdx.x * 32;
    for (int idx = tid; idx < 32 * 128; idx += 256) {
        int m = idx >> 7, k = idx & 127;
        int n = nbase + m;
        XT[k * TPAD + m] = (n < N) ? X[n * HDIM + k] : 0.f;
    }
    __syncthreads();
    const int c  = tid & 63;
    const int mb = (tid >> 6) << 3;
    float acc[8][2];
#pragma unroll
    for (int i = 0; i < 8; ++i) { acc[i][0] = 0.f; acc[i][1] = 0.f; }
    for (int k = 0; k < 128; ++k) {
        const float* xr = &XT[k * TPAD + mb];
        float4 a0 = *(const float4*)(xr);
        float4 a1 = *(const float4*)(xr + 4);
        float a[8] = {a0.x, a0.y, a0.z, a0.w, a1.x, a1.y, a1.z, a1.w};
        float b0 = W[k * HDIM + c];
        float b1 = W[k * HDIM + c + 64];
#pragma unroll
        for (int i = 0; i < 8; ++i) {
            acc[i][0] = fmaf(a[i], b0, acc[i][0]);
            acc[i][1] = fmaf(a[i], b1, acc[i][1]);
        }
    }
#pragma unroll
    for (int i = 0; i < 8; ++i) {
        int n = nbase + mb + i;
        if (n < N) {
            Y[n * HDIM + c]      = acc[i][0];
            Y[n * HDIM + c + 64] = acc[i][1];
        }
    }
}

__global__ void gemm12_kernel(const float* __restrict__ X, const float* __restrict__ W2,
                              float* __restrict__ Y, int N)
{
    int idx = blockIdx.x * 256 + threadIdx.x;
    int n = idx / ODIM, c = idx - n * ODIM;
    if (n >= N) return;
    float acc = 0.f;
    for (int k = 0; k < 128; ++k) acc = fmaf(X[n * HDIM + k], W2[k * ODIM + c], acc);
    Y[n * ODIM + c] = acc;
}

__global__ __launch_bounds__(128) void agg128_kernel(const float* __restrict__ hW,
        const int* __restrict__ row_ptr, const int* __restrict__ degi,
        const int* __restrict__ csr_src, const float* __restrict__ dinv,
        const float* __restrict__ bias, float* __restrict__ out, int N, int do_relu)
{
    int n = blockIdx.x;
    int c = threadIdx.x;
    float dn = dinv[n];
    float acc = hW[n * HDIM + c] * dn * dn;
    int start = row_ptr[n];
    int cnt = degi[n];
    for (int i = 0; i < cnt; ++i) {
        int s = csr_src[start + i];
        acc = fmaf(hW[s * HDIM + c], dinv[s] * dn, acc);
    }
    float v = acc + bias[c];
    if (do_relu) v = fmaxf(v, 0.f);
    out[n * HDIM + c] = v;
}

__global__ void agg12_kernel(const float* __restrict__ hW, const int* __restrict__ row_ptr,
        const int* __restrict__ degi, const int* __restrict__ csr_src,
        const float* __restrict__ dinv, const float* __restrict__ b2,
        float* __restrict__ out, int N)
{
    int idx = blockIdx.x * 256 + threadIdx.x;
    int n = idx / ODIM, c = idx - n * ODIM;
    if (n >= N) return;
    float dn = dinv[n];
    float acc = hW[n * ODIM + c] * dn * dn;
    int start = row_ptr[n], cnt = degi[n];
    for (int i = 0; i < cnt; ++i) {
        int s = csr_src[start + i];
        acc = fmaf(hW[s * ODIM + c], dinv[s] * dn, acc);
    }
    out[n * ODIM + c] = acc + b2[c];
}

extern "C" void kernel_launch(void* const* d_in, const int* in_sizes, int n_in,
                              void* d_out, int out_size, void* d_ws, size_t ws_size,
                              hipStream_t stream)
{
    const float* x     = (const float*)d_in[0];
    const int*   ei    = (const int*)d_in[1];
    const float* Wih0  = (const float*)d_in[2];
    const float* Whh0  = (const float*)d_in[3];
    const float* bih0  = (const float*)d_in[4];
    const float* bhh0  = (const float*)d_in[5];
    const float* Wih1  = (const float*)d_in[6];
    const float* Whh1  = (const float*)d_in[7];
    const float* bih1  = (const float*)d_in[8];
    const float* bhh1  = (const float*)d_in[9];
    const float* W0    = (const float*)d_in[10];
    const float* b0    = (const float*)d_in[11];
    const float* W1    = (const float*)d_in[12];
    const float* b1    = (const float*)d_in[13];
    const float* W2    = (const float*)d_in[14];
    const float* b2    = (const float*)d_in[15];
    float* out = (float*)d_out;

    const int N = in_sizes[0] / (TT * 2);
    const int E = in_sizes[1] / 2;

    // ---- workspace layout ----
    unsigned short* Wpk = (unsigned short*)d_ws;          // 416*64*8 = 212992 bf16 = 425984 B (16B-aligned)
    float* fbase = (float*)((char*)d_ws + 425984);
    float* hbuf = fbase;                                  // N*128
    float* buf1 = hbuf + (size_t)N * HDIM;                // N*128
    float* buf2 = buf1 + (size_t)N * HDIM;                // N*128
    float* dinv = buf2 + (size_t)N * HDIM;                // N
    int* degi    = (int*)(dinv + N);                      // N
    int* fill    = degi + N;                              // N
    int* counter = fill + N;                              // 1
    int* row_ptr = counter + 1;                           // N
    int* csr_src = row_ptr + N;                           // E

    hipMemsetAsync(degi, 0, (size_t)(2 * N + 1) * sizeof(int), stream);

    pack_kernel<<<(416 * 64 + 255) / 256, 256, 0, stream>>>(
        Wih0, Whh0, bih0, bhh0, Wih1, Whh1, bih1, bhh1, Wpk);

    lstm_mfma_kernel<<<(N + MB - 1) / MB, 256, 0, stream>>>(x, Wpk, hbuf, N);

    deg_count_kernel<<<(E + 255) / 256, 256, 0, stream>>>(ei, degi, E);
    row_alloc_kernel<<<(N + 255) / 256, 256, 0, stream>>>(degi, row_ptr, dinv, counter, N);
    csr_fill_kernel<<<(E + 255) / 256, 256, 0, stream>>>(ei, row_ptr, fill, csr_src, E);

    gemm128_kernel<<<(N + 31) / 32, 256, 0, stream>>>(hbuf, W0, buf1, N);
    agg128_kernel<<<N, 128, 0, stream>>>(buf1, row_ptr, degi, csr_src, dinv, b0, buf2, N, 1);
    gemm128_kernel<<<(N + 31) / 32, 256, 0, stream>>>(buf2, W1, buf1, N);
    agg128_kernel<<<N, 128, 0, stream>>>(buf1, row_ptr, degi, csr_src, dinv, b1, buf2, N, 1);
    gemm12_kernel<<<((size_t)N * ODIM + 255) / 256, 256, 0, stream>>>(buf2, W2, buf1, N);
    agg12_kernel<<<((size_t)N * ODIM + 255) / 256, 256, 0, stream>>>(
        buf1, row_ptr, degi, csr_src, dinv, b2, out, N);
}

// Round 3
// 2023.841 us; speedup vs baseline: 2.3014x; 1.0927x over previous
//
#include <hip/hip_runtime.h>
#include <hip/hip_bf16.h>

#define TT 12
#define HDIM 128
#define ODIM 12
#define MB 32          // LSTM nodes per block (32 => acc[4] per wave, no spill)
#define STR 148        // hA row stride in bf16 elements (296 B)
#define TPAD 36        // fp32 GCN gemm LDS pad

typedef short bf16x8 __attribute__((ext_vector_type(8)));
typedef short bf16x4 __attribute__((ext_vector_type(4)));
typedef float f32x16 __attribute__((ext_vector_type(16)));

__device__ __forceinline__ float fastrcp(float x) { return __builtin_amdgcn_rcpf(x); }
__device__ __forceinline__ float sigf(float x) { return fastrcp(1.f + __expf(-x)); }
__device__ __forceinline__ float tanh_fast(float x) { return 1.f - 2.f * fastrcp(1.f + __expf(2.f * x)); }
__device__ __forceinline__ unsigned short f2bf(float f) {
    union { float f; unsigned int u; } v; v.f = f;
    unsigned int r = v.u + 0x7FFFu + ((v.u >> 16) & 1u);
    return (unsigned short)(r >> 16);
}

// ---------------- weight pre-pack into MFMA B-fragment order ----------------
// slot = {mat0: cb*9+s (0..143)} {mat1: +144} {mat2: cb*8+s +288}
// element = Wpk[(slot*64 + lane)*8 + j];  B[k][col]: col=cb*32+(lane&31), k=s*16+(lane>>5)*8+j
__global__ void pack_kernel(const float* __restrict__ Wih0, const float* __restrict__ Whh0,
                            const float* __restrict__ bih0, const float* __restrict__ bhh0,
                            const float* __restrict__ Wih1, const float* __restrict__ Whh1,
                            const float* __restrict__ bih1, const float* __restrict__ bhh1,
                            unsigned short* __restrict__ Wpk)
{
    int idx = blockIdx.x * 256 + threadIdx.x;
    if (idx >= 416 * 64) return;
    int lane = idx & 63;
    int slot = idx >> 6;
    int mat, cb, s;
    if (slot < 144)      { mat = 0; cb = slot / 9; s = slot % 9; }
    else if (slot < 288) { mat = 1; cb = (slot - 144) / 9; s = (slot - 144) % 9; }
    else                 { mat = 2; cb = (slot - 288) / 8; s = (slot - 288) % 8; }
    int col = cb * 32 + (lane & 31);
#pragma unroll
    for (int j = 0; j < 8; ++j) {
        int k = s * 16 + ((lane >> 5) << 3) + j;
        float v = 0.f;
        if (mat == 0) {
            if (k < 128)       v = Whh0[col * 128 + k];
            else if (k == 128) v = Wih0[col * 2 + 0];
            else if (k == 129) v = Wih0[col * 2 + 1];
            else if (k == 130) v = bih0[col] + bhh0[col];
        } else if (mat == 1) {
            if (k < 128)       v = Wih1[col * 128 + k];
            else if (k == 130) v = bih1[col] + bhh1[col];
        } else {
            v = Whh1[col * 128 + k];
        }
        Wpk[((size_t)(slot * 64 + lane) << 3) + j] = f2bf(v);
    }
}

// ---------------- fused 2-layer LSTM, bf16 MFMA, 32-node blocks ----------------
template<int S>
__device__ __forceinline__ void mfma_gemm(const unsigned short* __restrict__ hA,
                                          const unsigned short* __restrict__ Bbase,
                                          int w, int ln, f32x16 (&acc)[4])
{
    const int ln31 = ln & 31, half = ln >> 5;
#pragma unroll
    for (int s = 0; s < S; ++s) {
        const unsigned short* pa = hA + ln31 * STR + s * 16 + half * 8;
        bf16x4 lo = *(const bf16x4*)pa;
        bf16x4 hi = *(const bf16x4*)(pa + 4);
        bf16x8 a = __builtin_shufflevector(lo, hi, 0, 1, 2, 3, 4, 5, 6, 7);
#pragma unroll
        for (int g = 0; g < 4; ++g) {
            int cb = g * 4 + w;
            bf16x8 b = *(const bf16x8*)(Bbase + (((cb * S + s) * 64 + ln) << 3));
            acc[g] = __builtin_amdgcn_mfma_f32_32x32x16_bf16(a, b, acc[g], 0, 0, 0);
        }
    }
}

__device__ __forceinline__ void zero_acc(f32x16 (&acc)[4])
{
#pragma unroll
    for (int g = 0; g < 4; ++g)
#pragma unroll
        for (int e = 0; e < 16; ++e) acc[g][e] = 0.f;
}

__global__ __launch_bounds__(256, 3) void lstm_mfma_kernel(
    const float* __restrict__ x,              // [N][12][2]
    const unsigned short* __restrict__ Wpk,   // packed B fragments
    float* __restrict__ hbuf,                 // [N][128] out (fp32 h1 at t=11)
    int N)
{
    __shared__ unsigned short hA0[2][MB * STR];
    __shared__ unsigned short hA1[MB * STR];
    __shared__ unsigned short xls[MB * TT * 2];

    const int tid = threadIdx.x;
    const int w = tid >> 6;
    const int ln = tid & 63;
    const int ln31 = ln & 31;
    const int half = ln >> 5;
    const int col = w * 32 + ln31;            // this wave's output channel
    const int nbase = blockIdx.x * MB;

    // stage x (coalesced), bf16
    for (int i = tid; i < MB * TT * 2; i += 256) {
        int n = nbase + i / (TT * 2);
        float v = (n < N) ? x[(size_t)nbase * (TT * 2) + i] : 0.f;
        xls[i] = f2bf(v);
    }
    for (int i = tid; i < MB * STR; i += 256) { hA0[0][i] = 0; hA0[1][i] = 0; hA1[i] = 0; }
    __syncthreads();
    // constant 1.0 column (k=130) for bias; x_0 at k=128..129
    if (tid < MB) { hA0[0][tid * STR + 130] = 0x3F80; hA0[1][tid * STR + 130] = 0x3F80; }
    if (tid < MB * 2) { int m = tid >> 1, c = tid & 1; hA0[0][m * STR + 128 + c] = xls[m * (TT * 2) + c]; }

    float c0[16], c1[16];
#pragma unroll
    for (int r = 0; r < 16; ++r) { c0[r] = 0.f; c1[r] = 0.f; }

    __syncthreads();

    int p = 0;
    for (int t = 0; t < TT; ++t) {
        int q = p ^ 1;
        // ---- layer 0: z0 = [h0_{t-1}, x_t, 1] @ B0 ----
        f32x16 acc[4];
        zero_acc(acc);
        mfma_gemm<9>(hA0[p], Wpk, w, ln, acc);
#pragma unroll
        for (int r = 0; r < 16; ++r) {
            float cn = sigf(acc[1][r]) * c0[r] + sigf(acc[0][r]) * tanh_fast(acc[2][r]);
            c0[r] = cn;
            float h = sigf(acc[3][r]) * tanh_fast(cn);
            int row = (r & 3) + 8 * (r >> 2) + 4 * half;
            hA0[q][row * STR + col] = f2bf(h);
        }
        if (t + 1 < TT) {
            if (tid < MB * 2) { int m = tid >> 1, c = tid & 1; hA0[q][m * STR + 128 + c] = xls[m * (TT * 2) + (t + 1) * 2 + c]; }
        }
        __syncthreads();   // h0_t + x_{t+1} visible; all waves done reading hA0[p]

        // ---- layer 1: z1 = [h0_t, ., 1] @ B1a + h1_{t-1} @ B1b ----
        zero_acc(acc);
        mfma_gemm<9>(hA0[q], Wpk + 73728, w, ln, acc);
        mfma_gemm<8>(hA1,    Wpk + 147456, w, ln, acc);
        __syncthreads();   // all waves done reading hA1

#pragma unroll
        for (int r = 0; r < 16; ++r) {
            float cn = sigf(acc[1][r]) * c1[r] + sigf(acc[0][r]) * tanh_fast(acc[2][r]);
            c1[r] = cn;
            float h = sigf(acc[3][r]) * tanh_fast(cn);
            int row = (r & 3) + 8 * (r >> 2) + 4 * half;
            if (t + 1 < TT) {
                hA1[row * STR + col] = f2bf(h);
            } else {
                int n = nbase + row;
                if (n < N) hbuf[n * HDIM + col] = h;
            }
        }
        p = q;
    }
}

// ---------------- GCN (unchanged this round) ----------------
__global__ void deg_count_kernel(const int* __restrict__ ei, int* __restrict__ degi, int E)
{
    int e = blockIdx.x * 256 + threadIdx.x;
    if (e < E) atomicAdd(&degi[ei[E + e]], 1);
}

__global__ void row_alloc_kernel(const int* __restrict__ degi, int* __restrict__ row_ptr,
                                 float* __restrict__ dinv, int* __restrict__ counter, int N)
{
    int n = blockIdx.x * 256 + threadIdx.x;
    int lane = threadIdx.x & 63;
    int v = (n < N) ? degi[n] : 0;
    int incl = v;
    for (int off = 1; off < 64; off <<= 1) {
        int u = __shfl_up(incl, off);
        if (lane >= off) incl += u;
    }
    int base = 0;
    if (lane == 63) base = atomicAdd(counter, incl);
    base = __shfl(base, 63);
    if (n < N) {
        row_ptr[n] = base + (incl - v);
        dinv[n] = rsqrtf((float)(v + 1));
    }
}

__global__ void csr_fill_kernel(const int* __restrict__ ei, const int* __restrict__ row_ptr,
                                int* __restrict__ fill, int* __restrict__ csr_src, int E)
{
    int e = blockIdx.x * 256 + threadIdx.x;
    if (e < E) {
        int d = ei[E + e];
        int p = atomicAdd(&fill[d], 1);
        csr_src[row_ptr[d] + p] = ei[e];
    }
}

__global__ __launch_bounds__(256) void gemm128_kernel(const float* __restrict__ X,
                                                      const float* __restrict__ W,
                                                      float* __restrict__ Y, int N)
{
    __shared__ float XT[128 * TPAD];
    const int tid = threadIdx.x;
    const int nbase = blockIdx.x * 32;
    for (int idx = tid; idx < 32 * 128; idx += 256) {
        int m = idx >> 7, k = idx & 127;
        int n = nbase + m;
        XT[k * TPAD + m] = (n < N) ? X[n * HDIM + k] : 0.f;
    }
    __syncthreads();
    const int c  = tid & 63;
    const int mb = (tid >> 6) << 3;
    float acc[8][2];
#pragma unroll
    for (int i = 0; i < 8; ++i) { acc[i][0] = 0.f; acc[i][1] = 0.f; }
    for (int k = 0; k < 128; ++k) {
        const float* xr = &XT[k * TPAD + mb];
        float4 a0 = *(const float4*)(xr);
        float4 a1 = *(const float4*)(xr + 4);
        float a[8] = {a0.x, a0.y, a0.z, a0.w, a1.x, a1.y, a1.z, a1.w};
        float b0 = W[k * HDIM + c];
        float b1 = W[k * HDIM + c + 64];
#pragma unroll
        for (int i = 0; i < 8; ++i) {
            acc[i][0] = fmaf(a[i], b0, acc[i][0]);
            acc[i][1] = fmaf(a[i], b1, acc[i][1]);
        }
    }
#pragma unroll
    for (int i = 0; i < 8; ++i) {
        int n = nbase + mb + i;
        if (n < N) {
            Y[n * HDIM + c]      = acc[i][0];
            Y[n * HDIM + c + 64] = acc[i][1];
        }
    }
}

__global__ void gemm12_kernel(const float* __restrict__ X, const float* __restrict__ W2,
                              float* __restrict__ Y, int N)
{
    int idx = blockIdx.x * 256 + threadIdx.x;
    int n = idx / ODIM, c = idx - n * ODIM;
    if (n >= N) return;
    float acc = 0.f;
    for (int k = 0; k < 128; ++k) acc = fmaf(X[n * HDIM + k], W2[k * ODIM + c], acc);
    Y[n * ODIM + c] = acc;
}

__global__ __launch_bounds__(128) void agg128_kernel(const float* __restrict__ hW,
        const int* __restrict__ row_ptr, const int* __restrict__ degi,
        const int* __restrict__ csr_src, const float* __restrict__ dinv,
        const float* __restrict__ bias, float* __restrict__ out, int N, int do_relu)
{
    int n = blockIdx.x;
    int c = threadIdx.x;
    float dn = dinv[n];
    float acc = hW[n * HDIM + c] * dn * dn;
    int start = row_ptr[n];
    int cnt = degi[n];
    for (int i = 0; i < cnt; ++i) {
        int s = csr_src[start + i];
        acc = fmaf(hW[s * HDIM + c], dinv[s] * dn, acc);
    }
    float v = acc + bias[c];
    if (do_relu) v = fmaxf(v, 0.f);
    out[n * HDIM + c] = v;
}

__global__ void agg12_kernel(const float* __restrict__ hW, const int* __restrict__ row_ptr,
        const int* __restrict__ degi, const int* __restrict__ csr_src,
        const float* __restrict__ dinv, const float* __restrict__ b2,
        float* __restrict__ out, int N)
{
    int idx = blockIdx.x * 256 + threadIdx.x;
    int n = idx / ODIM, c = idx - n * ODIM;
    if (n >= N) return;
    float dn = dinv[n];
    float acc = hW[n * ODIM + c] * dn * dn;
    int start = row_ptr[n], cnt = degi[n];
    for (int i = 0; i < cnt; ++i) {
        int s = csr_src[start + i];
        acc = fmaf(hW[s * ODIM + c], dinv[s] * dn, acc);
    }
    out[n * ODIM + c] = acc + b2[c];
}

extern "C" void kernel_launch(void* const* d_in, const int* in_sizes, int n_in,
                              void* d_out, int out_size, void* d_ws, size_t ws_size,
                              hipStream_t stream)
{
    const float* x     = (const float*)d_in[0];
    const int*   ei    = (const int*)d_in[1];
    const float* Wih0  = (const float*)d_in[2];
    const float* Whh0  = (const float*)d_in[3];
    const float* bih0  = (const float*)d_in[4];
    const float* bhh0  = (const float*)d_in[5];
    const float* Wih1  = (const float*)d_in[6];
    const float* Whh1  = (const float*)d_in[7];
    const float* bih1  = (const float*)d_in[8];
    const float* bhh1  = (const float*)d_in[9];
    const float* W0    = (const float*)d_in[10];
    const float* b0    = (const float*)d_in[11];
    const float* W1    = (const float*)d_in[12];
    const float* b1    = (const float*)d_in[13];
    const float* W2    = (const float*)d_in[14];
    const float* b2    = (const float*)d_in[15];
    float* out = (float*)d_out;

    const int N = in_sizes[0] / (TT * 2);
    const int E = in_sizes[1] / 2;

    unsigned short* Wpk = (unsigned short*)d_ws;          // 416*64*8 bf16 = 425984 B
    float* fbase = (float*)((char*)d_ws + 425984);
    float* hbuf = fbase;                                  // N*128
    float* buf1 = hbuf + (size_t)N * HDIM;                // N*128
    float* buf2 = buf1 + (size_t)N * HDIM;                // N*128
    float* dinv = buf2 + (size_t)N * HDIM;                // N
    int* degi    = (int*)(dinv + N);                      // N
    int* fill    = degi + N;                              // N
    int* counter = fill + N;                              // 1
    int* row_ptr = counter + 1;                           // N
    int* csr_src = row_ptr + N;                           // E

    hipMemsetAsync(degi, 0, (size_t)(2 * N + 1) * sizeof(int), stream);

    pack_kernel<<<(416 * 64 + 255) / 256, 256, 0, stream>>>(
        Wih0, Whh0, bih0, bhh0, Wih1, Whh1, bih1, bhh1, Wpk);

    lstm_mfma_kernel<<<(N + MB - 1) / MB, 256, 0, stream>>>(x, Wpk, hbuf, N);

    deg_count_kernel<<<(E + 255) / 256, 256, 0, stream>>>(ei, degi, E);
    row_alloc_kernel<<<(N + 255) / 256, 256, 0, stream>>>(degi, row_ptr, dinv, counter, N);
    csr_fill_kernel<<<(E + 255) / 256, 256, 0, stream>>>(ei, row_ptr, fill, csr_src, E);

    gemm128_kernel<<<(N + 31) / 32, 256, 0, stream>>>(hbuf, W0, buf1, N);
    agg128_kernel<<<N, 128, 0, stream>>>(buf1, row_ptr, degi, csr_src, dinv, b0, buf2, N, 1);
    gemm128_kernel<<<(N + 31) / 32, 256, 0, stream>>>(buf2, W1, buf1, N);
    agg128_kernel<<<N, 128, 0, stream>>>(buf1, row_ptr, degi, csr_src, dinv, b1, buf2, N, 1);
    gemm12_kernel<<<((size_t)N * ODIM + 255) / 256, 256, 0, stream>>>(buf2, W2, buf1, N);
    agg12_kernel<<<((size_t)N * ODIM + 255) / 256, 256, 0, stream>>>(
        buf1, row_ptr, degi, csr_src, dinv, b2, out, N);
}

// Round 4
// 1491.265 us; speedup vs baseline: 3.1233x; 1.3571x over previous
//
#include <hip/hip_runtime.h>
#include <hip/hip_bf16.h>

#define TT 12
#define HDIM 128
#define ODIM 12
#define MBX 128        // LSTM nodes per block (8 waves x 64 nodes/wave over 2 row-blocks)
#define KS 136         // hA row stride in shorts (272 B = 68 dwords == 4 mod 32 -> canonical b128 pattern)
#define TPAD 36        // fp32 GCN gemm LDS pad

typedef short bf16x8 __attribute__((ext_vector_type(8)));
typedef float f32x16 __attribute__((ext_vector_type(16)));

__device__ __forceinline__ float fastrcp(float x) { return __builtin_amdgcn_rcpf(x); }
__device__ __forceinline__ float sigf(float x) { return fastrcp(1.f + __expf(-x)); }
__device__ __forceinline__ float tanh_fast(float x) { return 1.f - 2.f * fastrcp(1.f + __expf(2.f * x)); }
__device__ __forceinline__ unsigned short f2bf(float f) {
    union { float f; unsigned int u; } v; v.f = f;
    unsigned int r = v.u + 0x7FFFu + ((v.u >> 16) & 1u);
    return (unsigned short)(r >> 16);
}

// ---------------- weight pre-pack into MFMA B-fragment order ----------------
// K=128 for all 3 matrices. slot = (mat*16 + cb)*8 + s  (384 slots x 1 KB = 384 KB)
// element = Wpk[(slot*64 + lane)*8 + j];  B[k][col]: col=cb*32+(lane&31), k=s*16+(lane>>5)*8+j
// mat0 = Whh0, mat1 = Wih1, mat2 = Whh1 (all [512][128] row-major)
__global__ void pack_kernel(const float* __restrict__ Whh0, const float* __restrict__ Wih1,
                            const float* __restrict__ Whh1, unsigned short* __restrict__ Wpk)
{
    int idx = blockIdx.x * 256 + threadIdx.x;
    if (idx >= 384 * 64) return;
    int lane = idx & 63;
    int slot = idx >> 6;
    int mat = slot >> 7;
    int rem = slot & 127;
    int cb = rem >> 3, s = rem & 7;
    int col = cb * 32 + (lane & 31);
    const float* src = (mat == 0) ? Whh0 : (mat == 1) ? Wih1 : Whh1;
#pragma unroll
    for (int j = 0; j < 8; ++j) {
        int k = s * 16 + ((lane >> 5) << 3) + j;
        Wpk[((size_t)(slot * 64 + lane) << 3) + j] = f2bf(src[col * 128 + k]);
    }
}

// ---------------- fused 2-layer LSTM, bf16 MFMA, 128-node blocks ----------------
__device__ __forceinline__ void gemm8(const unsigned short* __restrict__ hA,
                                      const unsigned short* __restrict__ Wm,
                                      int wsub, int nh, int ln, f32x16 (&acc)[2][4])
{
    const int ln31 = ln & 31, half = ln >> 5;
#pragma unroll
    for (int s = 0; s < 8; ++s) {
        bf16x8 a[2];
#pragma unroll
        for (int rb = 0; rb < 2; ++rb)
            a[rb] = *(const bf16x8*)(hA + (nh * 64 + rb * 32 + ln31) * KS + s * 16 + half * 8);
#pragma unroll
        for (int g = 0; g < 4; ++g) {
            int cb = g * 4 + wsub;
            bf16x8 b = *(const bf16x8*)(Wm + (((cb * 8 + s) * 64 + ln) << 3));
            acc[0][g] = __builtin_amdgcn_mfma_f32_32x32x16_bf16(a[0], b, acc[0][g], 0, 0, 0);
            acc[1][g] = __builtin_amdgcn_mfma_f32_32x32x16_bf16(a[1], b, acc[1][g], 0, 0, 0);
        }
    }
}

__device__ __forceinline__ void zero_acc(f32x16 (&acc)[2][4])
{
#pragma unroll
    for (int rb = 0; rb < 2; ++rb)
#pragma unroll
        for (int g = 0; g < 4; ++g)
#pragma unroll
            for (int e = 0; e < 16; ++e) acc[rb][g][e] = 0.f;
}

__global__ __launch_bounds__(512, 2) void lstm_mfma_kernel(
    const float* __restrict__ x,              // [N][12][2]
    const unsigned short* __restrict__ Wpk,   // packed B fragments (384 KB)
    const float* __restrict__ Wih0,           // [512][2]
    const float* __restrict__ bih0, const float* __restrict__ bhh0,
    const float* __restrict__ bih1, const float* __restrict__ bhh1,
    float* __restrict__ hbuf,                 // [N][128] out (fp32 h1 at t=11)
    int N)
{
    __shared__ unsigned short hA0[2][MBX * KS];   // h0 ping-pong
    __shared__ unsigned short hA1[MBX * KS];      // h1
    __shared__ float xls[MBX * TT * 2];           // fp32 x tile [node][t][c]

    const int tid  = threadIdx.x;
    const int w    = tid >> 6;
    const int ln   = tid & 63;
    const int ln31 = ln & 31;
    const int half = ln >> 5;
    const int wsub = w & 3;       // channel-block group
    const int nh   = w >> 2;      // node half (0: nodes 0-63, 1: 64-127)
    const int col  = wsub * 32 + ln31;   // this thread's output channel (0..127)
    const int nbase = blockIdx.x * MBX;

    // stage x (coalesced fp32)
    for (int i = tid; i < MBX * TT * 2; i += 512) {
        int n = nbase + i / (TT * 2);
        xls[i] = (n < N) ? x[(size_t)nbase * (TT * 2) + i] : 0.f;
    }
    // zero h buffers (t=0 state)
    for (int i = tid; i < MBX * KS; i += 512) { hA0[0][i] = 0; hA1[i] = 0; }

    // per-thread epilogue constants: 4 gates for channel `col`
    float wx0[4], wx1[4], br0[4], br1[4];
#pragma unroll
    for (int g = 0; g < 4; ++g) {
        int row = (g << 7) + col;
        wx0[g] = Wih0[row * 2 + 0];
        wx1[g] = Wih0[row * 2 + 1];
        br0[g] = bih0[row] + bhh0[row];
        br1[g] = bih1[row] + bhh1[row];
    }

    float c0[2][16], c1[2][16];
#pragma unroll
    for (int rb = 0; rb < 2; ++rb)
#pragma unroll
        for (int r = 0; r < 16; ++r) { c0[rb][r] = 0.f; c1[rb][r] = 0.f; }

    __syncthreads();

    const unsigned short* Wm0 = Wpk;            // Whh0
    const unsigned short* Wm1 = Wpk + 65536;    // Wih1
    const unsigned short* Wm2 = Wpk + 131072;   // Whh1

    int p = 0;
    for (int t = 0; t < TT; ++t) {
        int q = p ^ 1;
        // ---- layer 0: z0 = h0_{t-1} @ Whh0^T (+ x/bias in epilogue) ----
        f32x16 acc[2][4];
        zero_acc(acc);
        gemm8(hA0[p], Wm0, wsub, nh, ln, acc);
#pragma unroll
        for (int rb = 0; rb < 2; ++rb) {
#pragma unroll
            for (int r = 0; r < 16; ++r) {
                int node = nh * 64 + rb * 32 + (r & 3) + 8 * (r >> 2) + 4 * half;
                float xa = xls[node * (TT * 2) + t * 2 + 0];
                float xb = xls[node * (TT * 2) + t * 2 + 1];
                float zi = acc[rb][0][r] + br0[0] + wx0[0] * xa + wx1[0] * xb;
                float zf = acc[rb][1][r] + br0[1] + wx0[1] * xa + wx1[1] * xb;
                float zg = acc[rb][2][r] + br0[2] + wx0[2] * xa + wx1[2] * xb;
                float zo = acc[rb][3][r] + br0[3] + wx0[3] * xa + wx1[3] * xb;
                float cn = sigf(zf) * c0[rb][r] + sigf(zi) * tanh_fast(zg);
                c0[rb][r] = cn;
                float h = sigf(zo) * tanh_fast(cn);
                hA0[q][node * KS + col] = f2bf(h);
            }
        }
        __syncthreads();   // B1: h0_t visible; all waves done reading hA0[p]

        // ---- layer 1: z1 = h0_t @ Wih1^T + h1_{t-1} @ Whh1^T ----
        zero_acc(acc);
        gemm8(hA0[q], Wm1, wsub, nh, ln, acc);
        gemm8(hA1,    Wm2, wsub, nh, ln, acc);
        __syncthreads();   // B2: all waves done reading hA1

#pragma unroll
        for (int rb = 0; rb < 2; ++rb) {
#pragma unroll
            for (int r = 0; r < 16; ++r) {
                int node = nh * 64 + rb * 32 + (r & 3) + 8 * (r >> 2) + 4 * half;
                float zi = acc[rb][0][r] + br1[0];
                float zf = acc[rb][1][r] + br1[1];
                float zg = acc[rb][2][r] + br1[2];
                float zo = acc[rb][3][r] + br1[3];
                float cn = sigf(zf) * c1[rb][r] + sigf(zi) * tanh_fast(zg);
                c1[rb][r] = cn;
                float h = sigf(zo) * tanh_fast(cn);
                if (t + 1 < TT) {
                    hA1[node * KS + col] = f2bf(h);
                } else {
                    int n = nbase + node;
                    if (n < N) hbuf[n * HDIM + col] = h;
                }
            }
        }
        p = q;
        // next-iteration B1 orders the hA1 writes before any hA1 read
    }
}

// ---------------- GCN (unchanged this round) ----------------
__global__ void deg_count_kernel(const int* __restrict__ ei, int* __restrict__ degi, int E)
{
    int e = blockIdx.x * 256 + threadIdx.x;
    if (e < E) atomicAdd(&degi[ei[E + e]], 1);
}

__global__ void row_alloc_kernel(const int* __restrict__ degi, int* __restrict__ row_ptr,
                                 float* __restrict__ dinv, int* __restrict__ counter, int N)
{
    int n = blockIdx.x * 256 + threadIdx.x;
    int lane = threadIdx.x & 63;
    int v = (n < N) ? degi[n] : 0;
    int incl = v;
    for (int off = 1; off < 64; off <<= 1) {
        int u = __shfl_up(incl, off);
        if (lane >= off) incl += u;
    }
    int base = 0;
    if (lane == 63) base = atomicAdd(counter, incl);
    base = __shfl(base, 63);
    if (n < N) {
        row_ptr[n] = base + (incl - v);
        dinv[n] = rsqrtf((float)(v + 1));
    }
}

__global__ void csr_fill_kernel(const int* __restrict__ ei, const int* __restrict__ row_ptr,
                                int* __restrict__ fill, int* __restrict__ csr_src, int E)
{
    int e = blockIdx.x * 256 + threadIdx.x;
    if (e < E) {
        int d = ei[E + e];
        int p = atomicAdd(&fill[d], 1);
        csr_src[row_ptr[d] + p] = ei[e];
    }
}

__global__ __launch_bounds__(256) void gemm128_kernel(const float* __restrict__ X,
                                                      const float* __restrict__ W,
                                                      float* __restrict__ Y, int N)
{
    __shared__ float XT[128 * TPAD];
    const int tid = threadIdx.x;
    const int nbase = blockIdx.x * 32;
    for (int idx = tid; idx < 32 * 128; idx += 256) {
        int m = idx >> 7, k = idx & 127;
        int n = nbase + m;
        XT[k * TPAD + m] = (n < N) ? X[n * HDIM + k] : 0.f;
    }
    __syncthreads();
    const int c  = tid & 63;
    const int mb = (tid >> 6) << 3;
    float acc[8][2];
#pragma unroll
    for (int i = 0; i < 8; ++i) { acc[i][0] = 0.f; acc[i][1] = 0.f; }
    for (int k = 0; k < 128; ++k) {
        const float* xr = &XT[k * TPAD + mb];
        float4 a0 = *(const float4*)(xr);
        float4 a1 = *(const float4*)(xr + 4);
        float a[8] = {a0.x, a0.y, a0.z, a0.w, a1.x, a1.y, a1.z, a1.w};
        float b0 = W[k * HDIM + c];
        float b1 = W[k * HDIM + c + 64];
#pragma unroll
        for (int i = 0; i < 8; ++i) {
            acc[i][0] = fmaf(a[i], b0, acc[i][0]);
            acc[i][1] = fmaf(a[i], b1, acc[i][1]);
        }
    }
#pragma unroll
    for (int i = 0; i < 8; ++i) {
        int n = nbase + mb + i;
        if (n < N) {
            Y[n * HDIM + c]      = acc[i][0];
            Y[n * HDIM + c + 64] = acc[i][1];
        }
    }
}

__global__ void gemm12_kernel(const float* __restrict__ X, const float* __restrict__ W2,
                              float* __restrict__ Y, int N)
{
    int idx = blockIdx.x * 256 + threadIdx.x;
    int n = idx / ODIM, c = idx - n * ODIM;
    if (n >= N) return;
    float acc = 0.f;
    for (int k = 0; k < 128; ++k) acc = fmaf(X[n * HDIM + k], W2[k * ODIM + c], acc);
    Y[n * ODIM + c] = acc;
}

__global__ __launch_bounds__(128) void agg128_kernel(const float* __restrict__ hW,
        const int* __restrict__ row_ptr, const int* __restrict__ degi,
        const int* __restrict__ csr_src, const float* __restrict__ dinv,
        const float* __restrict__ bias, float* __restrict__ out, int N, int do_relu)
{
    int n = blockIdx.x;
    int c = threadIdx.x;
    float dn = dinv[n];
    float acc = hW[n * HDIM + c] * dn * dn;
    int start = row_ptr[n];
    int cnt = degi[n];
    for (int i = 0; i < cnt; ++i) {
        int s = csr_src[start + i];
        acc = fmaf(hW[s * HDIM + c], dinv[s] * dn, acc);
    }
    float v = acc + bias[c];
    if (do_relu) v = fmaxf(v, 0.f);
    out[n * HDIM + c] = v;
}

__global__ void agg12_kernel(const float* __restrict__ hW, const int* __restrict__ row_ptr,
        const int* __restrict__ degi, const int* __restrict__ csr_src,
        const float* __restrict__ dinv, const float* __restrict__ b2,
        float* __restrict__ out, int N)
{
    int idx = blockIdx.x * 256 + threadIdx.x;
    int n = idx / ODIM, c = idx - n * ODIM;
    if (n >= N) return;
    float dn = dinv[n];
    float acc = hW[n * ODIM + c] * dn * dn;
    int start = row_ptr[n], cnt = degi[n];
    for (int i = 0; i < cnt; ++i) {
        int s = csr_src[start + i];
        acc = fmaf(hW[s * ODIM + c], dinv[s] * dn, acc);
    }
    out[n * ODIM + c] = acc + b2[c];
}

extern "C" void kernel_launch(void* const* d_in, const int* in_sizes, int n_in,
                              void* d_out, int out_size, void* d_ws, size_t ws_size,
                              hipStream_t stream)
{
    const float* x     = (const float*)d_in[0];
    const int*   ei    = (const int*)d_in[1];
    const float* Wih0  = (const float*)d_in[2];
    const float* Whh0  = (const float*)d_in[3];
    const float* bih0  = (const float*)d_in[4];
    const float* bhh0  = (const float*)d_in[5];
    const float* Wih1  = (const float*)d_in[6];
    const float* Whh1  = (const float*)d_in[7];
    const float* bih1  = (const float*)d_in[8];
    const float* bhh1  = (const float*)d_in[9];
    const float* W0    = (const float*)d_in[10];
    const float* b0    = (const float*)d_in[11];
    const float* W1    = (const float*)d_in[12];
    const float* b1    = (const float*)d_in[13];
    const float* W2    = (const float*)d_in[14];
    const float* b2    = (const float*)d_in[15];
    float* out = (float*)d_out;

    const int N = in_sizes[0] / (TT * 2);
    const int E = in_sizes[1] / 2;

    unsigned short* Wpk = (unsigned short*)d_ws;          // 384*64*8 shorts = 393216 B
    float* fbase = (float*)((char*)d_ws + 393216);
    float* hbuf = fbase;                                  // N*128
    float* buf1 = hbuf + (size_t)N * HDIM;                // N*128
    float* buf2 = buf1 + (size_t)N * HDIM;                // N*128
    float* dinv = buf2 + (size_t)N * HDIM;                // N
    int* degi    = (int*)(dinv + N);                      // N
    int* fill    = degi + N;                              // N
    int* counter = fill + N;                              // 1
    int* row_ptr = counter + 1;                           // N
    int* csr_src = row_ptr + N;                           // E

    hipMemsetAsync(degi, 0, (size_t)(2 * N + 1) * sizeof(int), stream);

    pack_kernel<<<(384 * 64 + 255) / 256, 256, 0, stream>>>(Whh0, Wih1, Whh1, Wpk);

    lstm_mfma_kernel<<<(N + MBX - 1) / MBX, 512, 0, stream>>>(
        x, Wpk, Wih0, bih0, bhh0, bih1, bhh1, hbuf, N);

    deg_count_kernel<<<(E + 255) / 256, 256, 0, stream>>>(ei, degi, E);
    row_alloc_kernel<<<(N + 255) / 256, 256, 0, stream>>>(degi, row_ptr, dinv, counter, N);
    csr_fill_kernel<<<(E + 255) / 256, 256, 0, stream>>>(ei, row_ptr, fill, csr_src, E);

    gemm128_kernel<<<(N + 31) / 32, 256, 0, stream>>>(hbuf, W0, buf1, N);
    agg128_kernel<<<N, 128, 0, stream>>>(buf1, row_ptr, degi, csr_src, dinv, b0, buf2, N, 1);
    gemm128_kernel<<<(N + 31) / 32, 256, 0, stream>>>(buf2, W1, buf1, N);
    agg128_kernel<<<N, 128, 0, stream>>>(buf1, row_ptr, degi, csr_src, dinv, b1, buf2, N, 1);
    gemm12_kernel<<<((size_t)N * ODIM + 255) / 256, 256, 0, stream>>>(buf2, W2, buf1, N);
    agg12_kernel<<<((size_t)N * ODIM + 255) / 256, 256, 0, stream>>>(
        buf1, row_ptr, degi, csr_src, dinv, b2, out, N);
}